// Round 11
// baseline (785.443 us; speedup 1.0000x reference)
//
#include <hip/hip_runtime.h>
#include <hip/hip_bf16.h>

// GCN encoder: 3 layers, N=100000 nodes, E=1250000 edges, 64 features.
// gcn(x) = relu(D^-1/2 (A+I) D^-1/2 (xW) + b)
// A1 = bf16(dinv.*(x@W1)) [gemm1]
// agg_mm(A1,W2): h1_d = relu(dinv_d*(A1_d+sum A1_s)+b1); A2 = bf16(dinv.*(h1@W2))
// agg_mm(A2,W3): h2_d = relu(dinv_d*(A2_d+sum A2_s)+b2); out = h2@W3 + b3
// R9: cooperative mega = 4x slower (grid.sync cross-XCD flush). Multi-kernel.
// R10: readlane matmul epilogue cost +48us/call (serialized VALU).
// R11: same fusion, proper epilogue: gather writes h rows to LDS tile,
//      then the proven b128/4x4-regtile k-loop computes h@W in-block.

#define WG 256
#define BSHIFT 9                 // 512 nodes per bucket
#define BSIZE  (1 << BSHIFT)
#define BCAP   8192              // slots per bucket (mean 6400, ~22 sigma margin)
#define PCHUNK 2048              // edges per partition block
#define XS_LD  68                // LDS tile leading dim: 16B-aligned, b128 reads

// Partition edges by dst-bucket into packed pairs ((dst&511)<<32 | src) in
// fixed per-bucket slabs. cur2 = pure counts (memset 0 before). LDS histogram
// -> 1 global atomic per touched bucket -> LDS-staged bucket-ordered output.
__global__ __launch_bounds__(WG) void partition(const int* __restrict__ ei,
                                                int* __restrict__ cur2,
                                                unsigned long long* __restrict__ pairs,
                                                int E) {
    __shared__ int hist[256];
    __shared__ int gbase[256];
    __shared__ int lb[256];
    __shared__ int wtot[4], wpre[4];
    __shared__ unsigned long long sp[PCHUNK];
    __shared__ int sd[PCHUNK];
    const int t = threadIdx.x;
    const int lane = t & 63, w = t >> 6;
    const int base = blockIdx.x * PCHUNK;
    const int total = min(PCHUNK, E - base);

    hist[t] = 0;
    __syncthreads();

    int s[8], d[8], r[8];
#pragma unroll
    for (int i = 0; i < 8; i++) {
        int e = base + i * WG + t;
        bool ok = e < E;
        s[i] = ok ? ei[e] : 0;
        d[i] = ok ? ei[E + e] : 0;
        r[i] = ok ? atomicAdd(&hist[d[i] >> BSHIFT], 1) : 0;
        if (!ok) d[i] = -1;
    }
    __syncthreads();

    int hv = hist[t];
    int old = (hv > 0) ? atomicAdd(&cur2[t], hv) : 0;
    gbase[t] = t * BCAP + old;

    int incl = hv;
#pragma unroll
    for (int ofs = 1; ofs < 64; ofs <<= 1) {
        int u = __shfl_up(incl, ofs);
        if (lane >= ofs) incl += u;
    }
    if (lane == 63) wtot[w] = incl;
    lb[t] = incl - hv;
    __syncthreads();
    if (t == 0) {
        int run = 0;
#pragma unroll
        for (int j = 0; j < 4; j++) { wpre[j] = run; run += wtot[j]; }
    }
    __syncthreads();

#pragma unroll
    for (int i = 0; i < 8; i++) {
        if (d[i] >= 0) {
            int b = d[i] >> BSHIFT;
            int slot = wpre[b >> 6] + lb[b] + r[i];
            sp[slot] = ((unsigned long long)(unsigned)(d[i] & (BSIZE - 1)) << 32) |
                       (unsigned)s[i];
            sd[slot] = gbase[b] + r[i];
        }
    }
    __syncthreads();

    for (int j = t; j < total; j += WG)
        pairs[sd[j]] = sp[j];
}

// Per-bucket CSR fill + off/dinv. Bucket base via in-block shfl scan of cur2.
__global__ __launch_bounds__(1024) void csr_local(const unsigned long long* __restrict__ pairs,
                                                  const int* __restrict__ cur2,
                                                  int* __restrict__ off,
                                                  float* __restrict__ dinv,
                                                  int* __restrict__ csr,
                                                  int N, int nbk, int E) {
    __shared__ int h[BSIZE];
    __shared__ int cur[BSIZE];
    __shared__ int wtot[16], wpre[16];
    __shared__ int bbs[256];
    const int b = blockIdx.x;
    const int t = threadIdx.x;
    const int lane = t & 63, w = t >> 6;
    const int node0 = b << BSHIFT;
    const int nlocal = min(BSIZE, N - node0);
    const int pstart = b * BCAP;
    const int pend = pstart + cur2[b];

    if (t < 256) {
        int v = (t < nbk) ? cur2[t] : 0;
        int incl = v;
#pragma unroll
        for (int ofs = 1; ofs < 64; ofs <<= 1) {
            int u = __shfl_up(incl, ofs);
            if (lane >= ofs) incl += u;
        }
        if (lane == 63) wtot[w] = incl;
        bbs[t] = incl - v;
    }
    __syncthreads();
    if (t == 0) {
        int run = 0;
#pragma unroll
        for (int j = 0; j < 4; j++) { wpre[j] = run; run += wtot[j]; }
        if (b == 0) off[N] = E;
    }
    __syncthreads();
    const int base_s = bbs[b] + wpre[b >> 6];

    if (t < BSIZE) h[t] = 0;
    __syncthreads();

    for (int e = pstart + t; e < pend; e += 1024)
        atomicAdd(&h[(int)(pairs[e] >> 32)], 1);
    __syncthreads();

    int deg = 0, incl = 0;
    if (t < BSIZE) {
        deg = h[t];
        incl = deg;
#pragma unroll
        for (int ofs = 1; ofs < 64; ofs <<= 1) {
            int u = __shfl_up(incl, ofs);
            if (lane >= ofs) incl += u;
        }
        if (lane == 63) wtot[w] = incl;
    }
    __syncthreads();
    if (t == 0) {
        int run = 0;
#pragma unroll
        for (int j = 0; j < 8; j++) { wpre[j] = run; run += wtot[j]; }
    }
    __syncthreads();
    if (t < nlocal) {
        int pos = base_s + wpre[w] + incl - deg;
        off[node0 + t] = pos;
        cur[t] = pos;
        dinv[node0 + t] = rsqrtf((float)(deg + 1));
    }
    __syncthreads();

    for (int e = pstart + t; e < pend; e += 1024) {
        unsigned long long p = pairs[e];
        int local = (int)(p >> 32);
        int src = (int)(p & 0xffffffffu);
        int pos = atomicAdd(&cur[local], 1);
        csr[pos] = src;
    }
}

// gemm1: A1 = bf16(dinv[row] * (x @ W1)).  64-row tile, 4x4 reg tile/thread.
__global__ __launch_bounds__(WG) void gemm_fused(
    const float* __restrict__ in, const float* __restrict__ W,
    const float* __restrict__ dinv, __hip_bfloat16* __restrict__ out1, int n_rows)
{
    __shared__ float Ws[64 * 64];
    __shared__ float xs[64 * XS_LD];

    const int t = threadIdx.x;
    const int row0 = blockIdx.x * 64;

    const float4* W4 = (const float4*)W;
    float4* Ws4 = (float4*)Ws;
#pragma unroll
    for (int i = 0; i < 4; i++) Ws4[i * WG + t] = W4[i * WG + t];

#pragma unroll
    for (int i = 0; i < 4; i++) {
        int j = i * WG + t;
        int rr = j >> 4;
        int c  = (j & 15) * 4;
        int row = row0 + rr;
        float4 v = make_float4(0.f, 0.f, 0.f, 0.f);
        if (row < n_rows)
            v = *(const float4*)(in + ((size_t)row << 6) + c);
        float* xp = xs + rr * XS_LD + c;
        xp[0] = v.x; xp[1] = v.y; xp[2] = v.z; xp[3] = v.w;
    }
    __syncthreads();

    const int fg = (t & 15) * 4;
    const int r0 = (t >> 4) * 4;
    float acc[4][4] = {};

#pragma unroll
    for (int kq = 0; kq < 64; kq += 4) {
        float4 xr[4];
#pragma unroll
        for (int r = 0; r < 4; r++)
            xr[r] = *(const float4*)(xs + (r0 + r) * XS_LD + kq);
#pragma unroll
        for (int kk = 0; kk < 4; kk++) {
            float4 wv = *(const float4*)(Ws + (kq + kk) * 64 + fg);
#pragma unroll
            for (int r = 0; r < 4; r++) {
                float xv = ((const float*)&xr[r])[kk];
                acc[r][0] = fmaf(xv, wv.x, acc[r][0]);
                acc[r][1] = fmaf(xv, wv.y, acc[r][1]);
                acc[r][2] = fmaf(xv, wv.z, acc[r][2]);
                acc[r][3] = fmaf(xv, wv.w, acc[r][3]);
            }
        }
    }

#pragma unroll
    for (int r = 0; r < 4; r++) {
        int row = row0 + r0 + r;
        if (row >= n_rows) break;
        float sc = dinv[row];
        union { __hip_bfloat16 h[4]; ushort4 u; } pk;
        pk.h[0] = __float2bfloat16(acc[r][0] * sc);
        pk.h[1] = __float2bfloat16(acc[r][1] * sc);
        pk.h[2] = __float2bfloat16(acc[r][2] * sc);
        pk.h[3] = __float2bfloat16(acc[r][3] * sc);
        *(ushort4*)((unsigned short*)out1 + ((size_t)row << 6) + fg) = pk.u;
    }
}

// Fused aggregate + next-layer GEMM.  Block = 64 nodes:
//  Phase A (gather): wave wv computes h = relu(dinv*(A[n]+sum A[csr])+b_in)
//    for its 16 nodes (lane = feature), writes rows into LDS tile hs.
//  Phase B (gemm): standard b128 / 4x4-regtile k-loop over hs @ Wn (Ws in LDS).
// out: bf16(dinv*o) (next gather array) or fp32 o + b_out (final output).
__global__ __launch_bounds__(WG) void agg_mm(
    const __hip_bfloat16* __restrict__ A,
    const int* __restrict__ off, const int* __restrict__ csr,
    const float* __restrict__ dinv, const float* __restrict__ b_in,
    const float* __restrict__ Wn, const float* __restrict__ b_out,
    void* __restrict__ outp, int out_bf16, int N)
{
    __shared__ float Ws[64 * 64];
    __shared__ float hs[64 * XS_LD];
    const int t = threadIdx.x;
    {
        const float4* W4 = (const float4*)Wn;
        float4* S4 = (float4*)Ws;
#pragma unroll
        for (int i = 0; i < 4; i++) S4[i * WG + t] = W4[i * WG + t];
    }
    const int lane = t & 63;
    const int wv = t >> 6;
    const float bin = b_in[lane];
    const int node0 = blockIdx.x * 64;

    // ---- Phase A: gather 16 nodes per wave into hs ----
    for (int i = 0; i < 16; i++) {
        int ln = wv * 16 + i;              // local row 0..63
        int node = node0 + ln;
        float h = 0.f;
        if (node < N) {
            int s0 = off[node], s1 = off[node + 1];
            float acc = __bfloat162float(A[((size_t)node << 6) + lane]);  // self
            int e = s0;
            for (; e + 4 <= s1; e += 4) {
                int i0 = csr[e], i1 = csr[e+1], i2 = csr[e+2], i3 = csr[e+3];
                float v0 = __bfloat162float(A[((size_t)i0 << 6) + lane]);
                float v1 = __bfloat162float(A[((size_t)i1 << 6) + lane]);
                float v2 = __bfloat162float(A[((size_t)i2 << 6) + lane]);
                float v3 = __bfloat162float(A[((size_t)i3 << 6) + lane]);
                acc += (v0 + v1) + (v2 + v3);
            }
            for (; e < s1; e++)
                acc += __bfloat162float(A[((size_t)csr[e] << 6) + lane]);
            h = fmaxf(fmaf(dinv[node], acc, bin), 0.f);
        }
        hs[ln * XS_LD + lane] = h;         // conflict-free row write
    }
    __syncthreads();

    // ---- Phase B: o = hs @ Wn (4x4 reg tile, b128 LDS reads) ----
    const int fg = (t & 15) * 4;
    const int r0 = (t >> 4) * 4;
    float acc[4][4] = {};

#pragma unroll
    for (int kq = 0; kq < 64; kq += 4) {
        float4 xr[4];
#pragma unroll
        for (int r = 0; r < 4; r++)
            xr[r] = *(const float4*)(hs + (r0 + r) * XS_LD + kq);
#pragma unroll
        for (int kk = 0; kk < 4; kk++) {
            float4 wvv = *(const float4*)(Ws + (kq + kk) * 64 + fg);
#pragma unroll
            for (int r = 0; r < 4; r++) {
                float xv = ((const float*)&xr[r])[kk];
                acc[r][0] = fmaf(xv, wvv.x, acc[r][0]);
                acc[r][1] = fmaf(xv, wvv.y, acc[r][1]);
                acc[r][2] = fmaf(xv, wvv.z, acc[r][2]);
                acc[r][3] = fmaf(xv, wvv.w, acc[r][3]);
            }
        }
    }

    float4 bp = b_out ? *(const float4*)(b_out + fg) : make_float4(0.f, 0.f, 0.f, 0.f);
#pragma unroll
    for (int r = 0; r < 4; r++) {
        int row = node0 + r0 + r;
        if (row >= N) break;
        if (out_bf16) {
            float sc = dinv[row];
            union { __hip_bfloat16 h[4]; ushort4 u; } pk;
            pk.h[0] = __float2bfloat16(acc[r][0] * sc);
            pk.h[1] = __float2bfloat16(acc[r][1] * sc);
            pk.h[2] = __float2bfloat16(acc[r][2] * sc);
            pk.h[3] = __float2bfloat16(acc[r][3] * sc);
            *(ushort4*)((unsigned short*)outp + ((size_t)row << 6) + fg) = pk.u;
        } else {
            float4 o;
            o.x = acc[r][0] + bp.x;
            o.y = acc[r][1] + bp.y;
            o.z = acc[r][2] + bp.z;
            o.w = acc[r][3] + bp.w;
            *(float4*)((float*)outp + ((size_t)row << 6) + fg) = o;
        }
    }
}

extern "C" void kernel_launch(void* const* d_in, const int* in_sizes, int n_in,
                              void* d_out, int out_size, void* d_ws, size_t ws_size,
                              hipStream_t stream) {
    const float* x  = (const float*)d_in[0];
    const int*   ei = (const int*)d_in[1];
    const float* W1 = (const float*)d_in[2];
    const float* b1 = (const float*)d_in[3];
    const float* W2 = (const float*)d_in[4];
    const float* b2 = (const float*)d_in[5];
    const float* W3 = (const float*)d_in[6];
    const float* b3 = (const float*)d_in[7];
    float* out = (float*)d_out;

    const int N = in_sizes[0] / 64;    // 100000
    const int E = in_sizes[1] / 2;     // 1250000
    const int nbk = (N + BSIZE - 1) / BSIZE;        // 196

    // workspace layout
    int*   off  = (int*)d_ws;                       // N+1
    int*   csr  = off + (N + 1);                    // E
    int*   cur2 = csr + E;                          // 256 (bucket counts)
    uintptr_t pa = (uintptr_t)(cur2 + 256);
    pa = (pa + 255) & ~(uintptr_t)255;
    float* dinv = (float*)pa;                       // N
    uintptr_t sa = (uintptr_t)(dinv + N);
    sa = (sa + 255) & ~(uintptr_t)255;
    // slab0: pairs (nbk*BCAP*8 = 12.85MB), reused as A1 (12.8MB bf16) after build
    unsigned long long* pairs = (unsigned long long*)sa;
    __hip_bfloat16* A1 = (__hip_bfloat16*)sa;
    size_t slab0 = (size_t)nbk * BCAP * 8;
    __hip_bfloat16* A2 = (__hip_bfloat16*)(sa + ((slab0 + 255) & ~(size_t)255));

    const int gG = (N + 63) / 64;                   // 1563
    const int gP = (E + PCHUNK - 1) / PCHUNK;       // 611

    hipMemsetAsync(cur2, 0, 256 * sizeof(int), stream);
    partition<<<gP,  WG,   0, stream>>>(ei, cur2, pairs, E);
    csr_local<<<nbk, 1024, 0, stream>>>(pairs, cur2, off, dinv, csr, N, nbk, E);

    // Layer 1 GEMM: A1 = bf16(dinv .* (x @ W1))
    gemm_fused<<<gG, WG, 0, stream>>>(x, W1, dinv, A1, N);
    // Layer 1 agg + Layer 2 GEMM: A2 = bf16(dinv .* (relu(dinv*(agg A1)+b1) @ W2))
    agg_mm<<<gG, WG, 0, stream>>>(A1, off, csr, dinv, b1, W2, nullptr, A2, 1, N);
    // Layer 2 agg + Layer 3 GEMM: out = relu(dinv*(agg A2)+b2) @ W3 + b3
    agg_mm<<<gG, WG, 0, stream>>>(A2, off, csr, dinv, b2, W3, b3, out, 0, N);
}